// Round 8
// baseline (288.809 us; speedup 1.0000x reference)
//
#include <hip/hip_runtime.h>
#include <math.h>

// FNO1d via fp16 MFMA, round 13: LDS minimalism + working prefetch.
// - Ws/Ms2/BasI/BasF NO LONGER staged in LDS: MFMA operand fragments are
//   16B per-lane gathers from small L2-resident arrays (Wh 8KB, Mph 4KB/b,
//   basI/basF 512KB shared by all 2048 blocks x 4 dispatches). Weights load
//   once at kernel start; BasI per tile; BasF inline in dft.
// - LDS = Ht (16.4KB) + Hout (17.4KB, UN-aliased) + bls = 34KB. Barriers
//   7 -> 4 per 2-tile block (alias barrier + staging barriers gone).
// - Tile-1 h prefetch now WORKS: issued after B1_0, drains at B2_0 which
//   sits after GEMM+GELU (~1500cy cover). R10 failed because the drain was
//   before compute; this schedule puts it after.
// - Transpose staging uses all 256 threads: 4 rows + 16 v_perm + 8 b64
//   writes each (was 128 threads x 8 rows).
// Carried: R9 2-tile register DFT accumulate + single atomic flush; R10/12
// proj-from-acc via shfl_xor; R12 lift w/ X-prefetch; parallel mode_mix w/
// in-place S zeroing; A&S erf GELU; role-swapped GEMM; XOR bank swizzle.
// MFMA layouts (m89/m91): A[m=lane&15][k=quad*8+j], B[k=quad*8+j][n=lane&15],
// C/D col=lane&15, row=quad*4+reg.

typedef _Float16 f16;
typedef _Float16 f16x2 __attribute__((ext_vector_type(2)));
typedef _Float16 f16x4 __attribute__((ext_vector_type(4)));
typedef _Float16 f16x8 __attribute__((ext_vector_type(8)));
typedef float    f32x2 __attribute__((ext_vector_type(2)));
typedef float    f32x4 __attribute__((ext_vector_type(4)));
typedef unsigned int u32;

#define BB 64
#define NN 8192

#define HT_S 64    // Ht [n=128][i=64], XOR-swizzled, stride 64 (no pad)
#define HO_S 136   // Hout [o=64][n=128]

// swizzle group for Ht row n
__device__ __forceinline__ int ht_swz(int n) { return ((n & 7) ^ ((n >> 3) & 7)) << 3; }

// Branchless GELU: 0.5*v*(1+erf(v/sqrt(2))) with A&S 7.1.26 erf, |err|<=1.5e-7.
__device__ __forceinline__ float gelu_f(float v) {
    float x  = v * 0.70710678118654752f;
    float ax = fabsf(x);
    float t  = __builtin_amdgcn_rcpf(fmaf(0.3275911f, ax, 1.0f));
    float p  = fmaf(1.061405429f, t, -1.453152027f);
    p = fmaf(p, t, 1.421413741f);
    p = fmaf(p, t, -0.284496736f);
    p = fmaf(p, t, 0.254829592f);
    p = p * t;
    float e  = __expf(-x * x);
    float er = fmaf(-p, e, 1.0f);     // erf(|x|)
    er = copysignf(er, x);
    return 0.5f * fmaf(v, er, v);
}

// ---------------------------------------------------------------- prep
__global__ __launch_bounds__(256) void fill_basis(f16* __restrict__ basF,
                                                  f16* __restrict__ basI,
                                                  const float* __restrict__ w_w,
                                                  f16* __restrict__ Wh,
                                                  float* __restrict__ Sz) {
    int n = blockIdx.x * 256 + threadIdx.x;   // 0..8191
    f16 row[32];
#pragma unroll
    for (int k = 0; k < 16; ++k) {
        float s, c;
        sincospif((float)(k * n) * (1.0f / 4096.0f), &s, &c);
        basF[k * NN + n]        = (f16)c;
        basF[(16 + k) * NN + n] = (f16)(-s);
        row[2 * k]     = (f16)c;
        row[2 * k + 1] = (f16)s;
    }
#pragma unroll
    for (int q = 0; q < 4; ++q) *(f16x8*)&basI[n * 32 + 8 * q] = *(f16x8*)&row[8 * q];
    Wh[n]        = (f16)w_w[n];
    Wh[n + 8192] = (f16)w_w[n + 8192];
    // zero S: 131072 floats / 8192 threads = 4 f32x4 each
    f32x4* S4 = (f32x4*)Sz;
    f32x4 z = {0.f, 0.f, 0.f, 0.f};
#pragma unroll
    for (int u = 0; u < 4; ++u) S4[n * 4 + u] = z;
}

// ---------------------------------------------------------------- mode mixing
// Grid BB, 1024 threads; block b is the SOLE reader of S[b], so after staging
// to LDS it re-zeroes S[b] in place for the next layer's atomics (no memset).
__global__ __launch_bounds__(1024) void mode_mix(float* __restrict__ S,
                                                 const float* __restrict__ wr,
                                                 const float* __restrict__ wi,
                                                 f16* __restrict__ Mph) {
    int b = blockIdx.x, t = threadIdx.x;
    __shared__ float Ss[32 * 66];
    if (t < 512) {
        f32x4 v = *(const f32x4*)&S[b * 2048 + t * 4];
        int rw = t >> 4, cl = (t & 15) * 4;
#pragma unroll
        for (int e = 0; e < 4; ++e) Ss[rw * 66 + cl + e] = v[e];
    }
    __syncthreads();
    // zero S[b] for the next layer's atomicAdd accumulation
    *(f32x2*)&S[b * 2048 + t * 2] = (f32x2){0.f, 0.f};

    int o = t >> 4, k = t & 15;
    const float* wrp = wr + o * 16 + k;
    const float* wip = wi + o * 16 + k;
    float ar = 0.f, ai = 0.f;
#pragma unroll 8
    for (int i = 0; i < 64; ++i) {
        float sr = Ss[k * 66 + i], si = Ss[(16 + k) * 66 + i];
        float wrv = wrp[i * 1024];
        float wiv = wip[i * 1024];
        ar = fmaf(sr, wrv, ar); ar = fmaf(-si, wiv, ar);
        ai = fmaf(sr, wiv, ai); ai = fmaf(si, wrv, ai);
    }
    float sc = (k == 0 ? 1.0f : 2.0f) * (1.0f / 8192.0f);
    f16x2 outv = { (f16)(sc * ar), (f16)(-sc * ai) };
    *(f16x2*)&Mph[b * 2048 + o * 32 + 2 * k] = outv;
}

// ---------------------------------------------------------------- DFT pieces
// sacc[mt] += BasF[mt*16+l15][n-tile] . Hout[o][n-tile]; BasF gathered from
// global (L2-hot, 512KB shared by all blocks).
__device__ __forceinline__ void dft_accum_g(const f16* Hout, const f16* __restrict__ basF_g,
                                            int n0, f32x4 sacc[2], int lane, int wv) {
    int q = lane >> 4, l15 = lane & 15;
    int o = (wv << 4) + l15;
#pragma unroll
    for (int ks = 0; ks < 4; ++ks) {
        f16x8 bh = *(const f16x8*)&Hout[o * HO_S + ks * 32 + q * 8];
#pragma unroll
        for (int mt = 0; mt < 2; ++mt) {
            f16x8 af = *(const f16x8*)&basF_g[(mt * 16 + l15) * NN + n0 + ks * 32 + q * 8];
            sacc[mt] = __builtin_amdgcn_mfma_f32_16x16x32_f16(af, bh, sacc[mt], 0, 0, 0);
        }
    }
}

__device__ __forceinline__ void dft_flush(const f32x4 sacc[2], float* __restrict__ S,
                                          int b, int lane, int wv) {
    int q = lane >> 4, l15 = lane & 15;
#pragma unroll
    for (int mt = 0; mt < 2; ++mt)
#pragma unroll
        for (int r = 0; r < 4; ++r)
            atomicAdd(&S[(b * 32 + mt * 16 + q * 4 + r) * 64 + (wv << 4) + l15],
                      sacc[mt][r]);
}

// ---------------------------------------------------------------- lifting (+DFT)
// Grid BB*32; 2 n-tiles/block; x prefetched upfront; atomics flushed once.
// (BasF here staged via LDS-free gathers as well.)
__global__ __launch_bounds__(256, 3) void lift_kernel(const float* __restrict__ x,
                                                      const float* __restrict__ p_w,
                                                      const float* __restrict__ p_b,
                                                      f16* __restrict__ h,
                                                      const f16* __restrict__ basF_g,
                                                      float* __restrict__ S) {
    __shared__ f16 Hout[64 * HO_S];
    int t = threadIdx.x;
    int b = blockIdx.x >> 5;
    int g = blockIdx.x & 31;
    int lane = t & 63, wv = t >> 6;
    int ns = (t & 15) << 3;

    float w0[4], w1[4], pb[4];
#pragma unroll
    for (int r = 0; r < 4; ++r) {
        int o = (t >> 4) + 16 * r;
        w0[r] = p_w[2 * o]; w1[r] = p_w[2 * o + 1]; pb[r] = p_b[o];
    }

    // prefetch both tiles' x (coalesced f32x4)
    f32x4 X[2][2];
#pragma unroll
    for (int tile = 0; tile < 2; ++tile) {
        int n0 = ((g << 1) + tile) << 7;
        X[tile][0] = *(const f32x4*)&x[(b << 13) + n0 + ns];
        X[tile][1] = *(const f32x4*)&x[(b << 13) + n0 + ns + 4];
    }

    f32x4 sacc[2] = {{0.f,0.f,0.f,0.f},{0.f,0.f,0.f,0.f}};
#pragma unroll
    for (int tile = 0; tile < 2; ++tile) {
        int n0 = ((g << 1) + tile) << 7;
#pragma unroll
        for (int r = 0; r < 4; ++r) {
            int o = (t >> 4) + 16 * r;
            f16 vals[8];
#pragma unroll
            for (int j = 0; j < 8; ++j) {
                int n = n0 + ns + j;
                float xv = X[tile][j >> 2][j & 3];
                vals[j] = (f16)(w0[r] * xv + w1[r] * ((float)n * (1.0f / 8191.0f)) + pb[r]);
            }
            *(f16x8*)&Hout[o * HO_S + ns] = *(f16x8*)vals;
            *(f16x8*)(h + (((size_t)(b * 64 + o)) << 13) + n0 + ns) = *(f16x8*)vals;
        }
        __syncthreads();
        dft_accum_g(Hout, basF_g, n0, sacc, lane, wv);
        if (tile == 0) __syncthreads();   // Hout reads done before restage
    }
    dft_flush(sacc, S, b, lane, wv);
}

// ---------------------------------------------------------------- fused layer
// 2 n-tiles/block, grid BB*32, 4 barriers total. DO_DFT=1: layers 0..2
// (GEMM+GELU -> h, fused DFT, atomics flushed once). DO_DFT=0: layer 3
// (projection from acc via shfl_xor).
template <int DO_DFT>
__global__ __launch_bounds__(256, 3) void layer_kernel(f16* __restrict__ h,
                                                       const f16* __restrict__ Wl_h,
                                                       const float* __restrict__ bl,
                                                       const f16* __restrict__ Mph,
                                                       const f16* __restrict__ basF_g,
                                                       const f16* __restrict__ basI_g,
                                                       float* __restrict__ S,
                                                       const float* __restrict__ q_w,
                                                       const float* __restrict__ q_b,
                                                       float* __restrict__ out) {
    __shared__ __align__(16) f16 Ht[128 * HT_S];
    __shared__ __align__(16) f16 Hout[DO_DFT ? 64 * HO_S : 8];
    __shared__ float bls[64];
    int t = threadIdx.x;
    int b = blockIdx.x >> 5;
    int g = blockIdx.x & 31;
    f16* hbase = h + (((size_t)(b * 64)) << 13);
    int lane = t & 63, wv = t >> 6;
    int q = lane >> 4, l15 = lane & 15;
    // transpose-staging coords (all 256 threads: 4 rows of an 8x8 block each)
    int blk = t >> 1, half = t & 1;
    int ig = blk >> 4, nb = blk & 15;
    int i0 = ig << 3, nst = nb << 3;
    int swz = nb & 7;
    int n0_0 = (g << 1) << 7, n0_1 = ((g << 1) + 1) << 7;
    f16* hbt0 = hbase + n0_0;
    f16* hbt1 = hbase + n0_1;

    // ---- B-frags gathered from global (drain at B1_0, covered by staging)
    f16x8 Bw[4][2], Bm[4];
#pragma unroll
    for (int ct = 0; ct < 4; ++ct) {
#pragma unroll
        for (int ks = 0; ks < 2; ++ks)
            Bw[ct][ks] = *(const f16x8*)&Wl_h[(ct * 16 + l15) * 64 + ks * 32 + q * 8];
        Bm[ct] = *(const f16x8*)&Mph[b * 2048 + (ct * 16 + l15) * 32 + q * 8];
    }
    if (t < 64) bls[t] = bl[t];

    // ---- stage tile0: 4-row loads + v_perm transpose + b64 swizzled writes
    f16x8 R0[4];
#pragma unroll
    for (int k = 0; k < 4; ++k)
        R0[k] = *(const f16x8*)(hbt0 + ((size_t)(i0 + half * 4 + k) << 13) + nst);
    // BasI frags tile0 (gather; drains at B1_0)
    f16x8 Ab0[2];
#pragma unroll
    for (int mtl = 0; mtl < 2; ++mtl)
        Ab0[mtl] = *(const f16x8*)&basI_g[(size_t)(n0_0 + (2 * wv + mtl) * 16 + l15) * 32 + q * 8];
    {
        const u32* rd = (const u32*)R0;
#pragma unroll
        for (int j = 0; j < 8; ++j) {
            u32 sel = (j & 1) ? 0x07060302u : 0x05040100u;
            int jd = j >> 1;
            u32 oo[2] __attribute__((aligned(8)));
            oo[0] = __builtin_amdgcn_perm(rd[4 + jd],  rd[jd],      sel);
            oo[1] = __builtin_amdgcn_perm(rd[12 + jd], rd[8 + jd],  sel);
            int col = (i0 ^ ((j ^ swz) << 3)) + half * 4;
            *(f16x4*)&Ht[(nst + j) * HT_S + col] = *(const f16x4*)oo;
        }
    }
    __syncthreads();                                   // B1_0

    // ---- prefetch tile1 (h rows + BasI); drains at B2_0 AFTER GEMM+GELU
    f16x8 R1[4];
#pragma unroll
    for (int k = 0; k < 4; ++k)
        R1[k] = *(const f16x8*)(hbt1 + ((size_t)(i0 + half * 4 + k) << 13) + nst);
    f16x8 Ab1[2];
#pragma unroll
    for (int mtl = 0; mtl < 2; ++mtl)
        Ab1[mtl] = *(const f16x8*)&basI_g[(size_t)(n0_1 + (2 * wv + mtl) * 16 + l15) * 32 + q * 8];

    float bv[4];
#pragma unroll
    for (int ct = 0; ct < 4; ++ct) bv[ct] = bls[ct * 16 + l15];

    f32x4 sacc[2] = {{0.f,0.f,0.f,0.f},{0.f,0.f,0.f,0.f}};

    // ================= tile 0 =================
    f32x4 acc[4][2];
#pragma unroll
    for (int ct = 0; ct < 4; ++ct)
#pragma unroll
        for (int m = 0; m < 2; ++m) acc[ct][m] = (f32x4){0.f, 0.f, 0.f, 0.f};
#pragma unroll
    for (int mtl = 0; mtl < 2; ++mtl) {
        int nrow = (2 * wv + mtl) * 16 + l15;
        const f16* hrow = &Ht[nrow * HT_S];
        int g3 = ht_swz(nrow);
#pragma unroll
        for (int ks = 0; ks < 2; ++ks) {
            f16x8 Ah = *(const f16x8*)&hrow[(ks * 32 + q * 8) ^ g3];
#pragma unroll
            for (int ct = 0; ct < 4; ++ct)
                acc[ct][mtl] = __builtin_amdgcn_mfma_f32_16x16x32_f16(
                    Ah, Bw[ct][ks], acc[ct][mtl], 0, 0, 0);
        }
#pragma unroll
        for (int ct = 0; ct < 4; ++ct)
            acc[ct][mtl] = __builtin_amdgcn_mfma_f32_16x16x32_f16(
                Ab0[mtl], Bm[ct], acc[ct][mtl], 0, 0, 0);
    }

    if (DO_DFT) {
        // GELU -> Hout (un-aliased; no barrier needed before writes)
#pragma unroll
        for (int ct = 0; ct < 4; ++ct) {
            int o = ct * 16 + l15;
#pragma unroll
            for (int mtl = 0; mtl < 2; ++mtl) {
                int nbase = (2 * wv + mtl) * 16 + q * 4;
                float gg[4];
#pragma unroll
                for (int r = 0; r < 4; ++r)
                    gg[r] = gelu_f(acc[ct][mtl][r] + bv[ct]);
                f16x2 lo = __builtin_bit_cast(f16x2, __builtin_amdgcn_cvt_pkrtz(gg[0], gg[1]));
                f16x2 hi = __builtin_bit_cast(f16x2, __builtin_amdgcn_cvt_pkrtz(gg[2], gg[3]));
                f16x4 pk = {lo[0], lo[1], hi[0], hi[1]};
                *(f16x4*)&Hout[o * HO_S + nbase] = pk;
            }
        }
        __syncthreads();                               // B2_0 (drains R1/Ab1 too)
        // h store tile0
#pragma unroll
        for (int r = 0; r < 4; ++r) {
            int o = (t >> 4) + 16 * r;
            int ns2 = (t & 15) << 3;
            *(f16x8*)(hbt0 + ((size_t)o << 13) + ns2) = *(f16x8*)&Hout[o * HO_S + ns2];
        }
        // stage tile1 Ht (perm only; Ht readers all done pre-B2_0)
        {
            const u32* rd = (const u32*)R1;
#pragma unroll
            for (int j = 0; j < 8; ++j) {
                u32 sel = (j & 1) ? 0x07060302u : 0x05040100u;
                int jd = j >> 1;
                u32 oo[2] __attribute__((aligned(8)));
                oo[0] = __builtin_amdgcn_perm(rd[4 + jd],  rd[jd],     sel);
                oo[1] = __builtin_amdgcn_perm(rd[12 + jd], rd[8 + jd], sel);
                int col = (i0 ^ ((j ^ swz) << 3)) + half * 4;
                *(f16x4*)&Ht[(nst + j) * HT_S + col] = *(const f16x4*)oo;
            }
        }
        dft_accum_g(Hout, basF_g, n0_0, sacc, lane, wv);
        __syncthreads();                               // B1_1
    } else {
        // projection tile0 directly from acc
        float qv[4];
#pragma unroll
        for (int ct = 0; ct < 4; ++ct) qv[ct] = q_w[ct * 16 + l15];
        float part[2][4] = {{0.f,0.f,0.f,0.f},{0.f,0.f,0.f,0.f}};
#pragma unroll
        for (int ct = 0; ct < 4; ++ct)
#pragma unroll
            for (int mtl = 0; mtl < 2; ++mtl)
#pragma unroll
                for (int r = 0; r < 4; ++r)
                    part[mtl][r] = fmaf(qv[ct], gelu_f(acc[ct][mtl][r] + bv[ct]), part[mtl][r]);
#pragma unroll
        for (int mtl = 0; mtl < 2; ++mtl)
#pragma unroll
            for (int r = 0; r < 4; ++r) {
                float s = part[mtl][r];
#pragma unroll
                for (int m = 1; m < 16; m <<= 1) s += __shfl_xor(s, m, 64);
                if (l15 == 0)
                    out[(b << 13) + n0_0 + (2 * wv + mtl) * 16 + q * 4 + r] = s + q_b[0];
            }
        __syncthreads();                               // Ht readers done
        {
            const u32* rd = (const u32*)R1;
#pragma unroll
            for (int j = 0; j < 8; ++j) {
                u32 sel = (j & 1) ? 0x07060302u : 0x05040100u;
                int jd = j >> 1;
                u32 oo[2] __attribute__((aligned(8)));
                oo[0] = __builtin_amdgcn_perm(rd[4 + jd],  rd[jd],     sel);
                oo[1] = __builtin_amdgcn_perm(rd[12 + jd], rd[8 + jd], sel);
                int col = (i0 ^ ((j ^ swz) << 3)) + half * 4;
                *(f16x4*)&Ht[(nst + j) * HT_S + col] = *(const f16x4*)oo;
            }
        }
        __syncthreads();                               // B1_1
    }

    // ================= tile 1 =================
#pragma unroll
    for (int ct = 0; ct < 4; ++ct)
#pragma unroll
        for (int m = 0; m < 2; ++m) acc[ct][m] = (f32x4){0.f, 0.f, 0.f, 0.f};
#pragma unroll
    for (int mtl = 0; mtl < 2; ++mtl) {
        int nrow = (2 * wv + mtl) * 16 + l15;
        const f16* hrow = &Ht[nrow * HT_S];
        int g3 = ht_swz(nrow);
#pragma unroll
        for (int ks = 0; ks < 2; ++ks) {
            f16x8 Ah = *(const f16x8*)&hrow[(ks * 32 + q * 8) ^ g3];
#pragma unroll
            for (int ct = 0; ct < 4; ++ct)
                acc[ct][mtl] = __builtin_amdgcn_mfma_f32_16x16x32_f16(
                    Ah, Bw[ct][ks], acc[ct][mtl], 0, 0, 0);
        }
#pragma unroll
        for (int ct = 0; ct < 4; ++ct)
            acc[ct][mtl] = __builtin_amdgcn_mfma_f32_16x16x32_f16(
                Ab1[mtl], Bm[ct], acc[ct][mtl], 0, 0, 0);
    }

    if (DO_DFT) {
#pragma unroll
        for (int ct = 0; ct < 4; ++ct) {
            int o = ct * 16 + l15;
#pragma unroll
            for (int mtl = 0; mtl < 2; ++mtl) {
                int nbase = (2 * wv + mtl) * 16 + q * 4;
                float gg[4];
#pragma unroll
                for (int r = 0; r < 4; ++r)
                    gg[r] = gelu_f(acc[ct][mtl][r] + bv[ct]);
                f16x2 lo = __builtin_bit_cast(f16x2, __builtin_amdgcn_cvt_pkrtz(gg[0], gg[1]));
                f16x2 hi = __builtin_bit_cast(f16x2, __builtin_amdgcn_cvt_pkrtz(gg[2], gg[3]));
                f16x4 pk = {lo[0], lo[1], hi[0], hi[1]};
                *(f16x4*)&Hout[o * HO_S + nbase] = pk;
            }
        }
        __syncthreads();                               // B2_1
#pragma unroll
        for (int r = 0; r < 4; ++r) {
            int o = (t >> 4) + 16 * r;
            int ns2 = (t & 15) << 3;
            *(f16x8*)(hbt1 + ((size_t)o << 13) + ns2) = *(f16x8*)&Hout[o * HO_S + ns2];
        }
        dft_accum_g(Hout, basF_g, n0_1, sacc, lane, wv);
        dft_flush(sacc, S, b, lane, wv);
    } else {
        float qv[4];
#pragma unroll
        for (int ct = 0; ct < 4; ++ct) qv[ct] = q_w[ct * 16 + l15];
        float part[2][4] = {{0.f,0.f,0.f,0.f},{0.f,0.f,0.f,0.f}};
#pragma unroll
        for (int ct = 0; ct < 4; ++ct)
#pragma unroll
            for (int mtl = 0; mtl < 2; ++mtl)
#pragma unroll
                for (int r = 0; r < 4; ++r)
                    part[mtl][r] = fmaf(qv[ct], gelu_f(acc[ct][mtl][r] + bv[ct]), part[mtl][r]);
#pragma unroll
        for (int mtl = 0; mtl < 2; ++mtl)
#pragma unroll
            for (int r = 0; r < 4; ++r) {
                float s = part[mtl][r];
#pragma unroll
                for (int m = 1; m < 16; m <<= 1) s += __shfl_xor(s, m, 64);
                if (l15 == 0)
                    out[(b << 13) + n0_1 + (2 * wv + mtl) * 16 + q * 4 + r] = s + q_b[0];
            }
    }
}

// ---------------------------------------------------------------- launch
extern "C" void kernel_launch(void* const* d_in, const int* in_sizes, int n_in,
                              void* d_out, int out_size, void* d_ws, size_t ws_size,
                              hipStream_t stream) {
    const float* x     = (const float*)d_in[0];
    const float* p_w   = (const float*)d_in[1];
    const float* p_b   = (const float*)d_in[2];
    const float* sc_wr = (const float*)d_in[3];
    const float* sc_wi = (const float*)d_in[4];
    const float* w_w   = (const float*)d_in[5];
    const float* w_b   = (const float*)d_in[6];
    const float* q_w   = (const float*)d_in[7];
    const float* q_b   = (const float*)d_in[8];
    float* out = (float*)d_out;

    char* ws = (char*)d_ws;
    f16*   h    = (f16*)ws;                               // 67,108,864 B
    float* S    = (float*)(ws + 67108864ull);             // 524,288 B
    f16*   Mph  = (f16*)(ws + 67633152ull);               // 262,144 B
    f16*   basF = (f16*)(ws + 67895296ull);               // 524,288 B
    f16*   basI = (f16*)(ws + 68419584ull);               // 524,288 B
    f16*   Wh   = (f16*)(ws + 68943872ull);               // 32,768 B

    hipLaunchKernelGGL(fill_basis, dim3(NN / 256), dim3(256), 0, stream,
                       basF, basI, w_w, Wh, S);
    hipLaunchKernelGGL(lift_kernel, dim3(BB * 32), dim3(256), 0, stream,
                       x, p_w, p_b, h, basF, S);
    for (int l = 0; l < 4; ++l) {
        hipLaunchKernelGGL(mode_mix, dim3(BB), dim3(1024), 0, stream,
                           S, sc_wr + l * 65536, sc_wi + l * 65536, Mph);
        if (l < 3) {
            hipLaunchKernelGGL((layer_kernel<1>), dim3(BB * 32), dim3(256), 0, stream,
                               h, Wh + l * 4096, w_b + l * 64, Mph, basF, basI, S,
                               q_w, q_b, out);
        } else {
            hipLaunchKernelGGL((layer_kernel<0>), dim3(BB * 32), dim3(256), 0, stream,
                               h, Wh + l * 4096, w_b + l * 64, Mph, basF, basI, S,
                               q_w, q_b, out);
        }
    }
}